// Round 4
// baseline (427.777 us; speedup 1.0000x reference)
//
#include <hip/hip_runtime.h>
#include <hip/hip_bf16.h>
#include <math.h>

#define NUM_ITEMS 50000
#define NUM_USERS 16384
#define H0 512
#define LAT 256
#define FP8_SCALE 64.0f   // weights ~±0.011 are subnormal in e4m3; x64 -> ~0.7 (3% rel err)
#define FP8_INV (1.0f / 64.0f)

typedef __attribute__((ext_vector_type(8))) short short8;
typedef __attribute__((ext_vector_type(4))) float floatx4;
typedef __attribute__((ext_vector_type(2))) float vf2;

__device__ __forceinline__ unsigned short f2bf(float f) {
    union { float f; unsigned i; } u; u.f = f;
    unsigned r = u.i + 0x7fff + ((u.i >> 16) & 1);   // RNE
    return (unsigned short)(r >> 16);
}
__device__ __forceinline__ float bfhi(unsigned v) {
    union { unsigned i; float f; } u; u.i = v & 0xffff0000u; return u.f;
}
__device__ __forceinline__ float bflo(unsigned v) {
    union { unsigned i; float f; } u; u.i = v << 16; return u.f;
}
__device__ __forceinline__ uint4 pack8(const float* v) {
    uint4 p;
    p.x = (unsigned)f2bf(v[0]) | ((unsigned)f2bf(v[1]) << 16);
    p.y = (unsigned)f2bf(v[2]) | ((unsigned)f2bf(v[3]) << 16);
    p.z = (unsigned)f2bf(v[4]) | ((unsigned)f2bf(v[5]) << 16);
    p.w = (unsigned)f2bf(v[6]) | ((unsigned)f2bf(v[7]) << 16);
    return p;
}
// pack 4 floats -> 4 fp8 e4m3 (OCP on gfx950)
__device__ __forceinline__ unsigned pkfp8_4(float a, float b, float c, float d) {
    int v = __builtin_amdgcn_cvt_pk_fp8_f32(a, b, 0, false);
    v = __builtin_amdgcn_cvt_pk_fp8_f32(c, d, v, true);
    return (unsigned)v;
}
__device__ __forceinline__ void fp8x4_to_f32(unsigned v, float* o) {
    vf2 lo = __builtin_amdgcn_cvt_pk_f32_fp8((int)v, false);
    vf2 hi = __builtin_amdgcn_cvt_pk_f32_fp8((int)v, true);
    o[0] = lo.x; o[1] = lo.y; o[2] = hi.x; o[3] = hi.y;
}

// ================= count: users (interactions) + users (targets) =================
__global__ __launch_bounds__(256) void count_kernel(const int* __restrict__ user, int* __restrict__ cntU,
                                                    const int* __restrict__ t_user, int* __restrict__ cntTU,
                                                    int n, int nt) {
    int i = (blockIdx.x * blockDim.x + threadIdx.x) * 4;
    if (i + 3 < n) {
        int4 u = *(const int4*)(user + i);
        atomicAdd(&cntU[u.x], 1); atomicAdd(&cntU[u.y], 1);
        atomicAdd(&cntU[u.z], 1); atomicAdd(&cntU[u.w], 1);
    } else {
        for (int k = i; k < n; ++k) atomicAdd(&cntU[user[k]], 1);
    }
    if (i + 3 < nt) {
        int4 t = *(const int4*)(t_user + i);
        atomicAdd(&cntTU[t.x], 1); atomicAdd(&cntTU[t.y], 1);
        atomicAdd(&cntTU[t.z], 1); atomicAdd(&cntTU[t.w], 1);
    } else {
        for (int k = i; k < nt; ++k) atomicAdd(&cntTU[t_user[k]], 1);
    }
}

// ================= dual exclusive scan (shfl-based, 2 barriers) =================
__device__ void scan_block(const int* __restrict__ cnt, int* __restrict__ offs,
                           int* __restrict__ cursor) {
    // 1024 threads, 16 elements each (16384 total)
    __shared__ int wsum_s[16];
    int t = threadIdx.x;
    int lane = t & 63, wid = t >> 6;
    int base = t * 16;
    int4 a = *(const int4*)(cnt + base);
    int4 b = *(const int4*)(cnt + base + 4);
    int4 c = *(const int4*)(cnt + base + 8);
    int4 d = *(const int4*)(cnt + base + 12);
    int s = a.x + a.y + a.z + a.w + b.x + b.y + b.z + b.w
          + c.x + c.y + c.z + c.w + d.x + d.y + d.z + d.w;
    // inclusive wave scan of per-thread sums
    int sc = s;
#pragma unroll
    for (int off = 1; off < 64; off <<= 1) {
        int v = __shfl_up(sc, off, 64);
        if (lane >= off) sc += v;
    }
    if (lane == 63) wsum_s[wid] = sc;
    __syncthreads();
    if (t < 16) {
        int w = wsum_s[t];
        int wsc = w;
#pragma unroll
        for (int off = 1; off < 16; off <<= 1) {
            int v = __shfl_up(wsc, off, 64);
            if (t >= off) wsc += v;
        }
        wsum_s[t] = wsc - w;    // exclusive wave prefix
    }
    __syncthreads();
    int run = wsum_s[wid] + (sc - s);   // global exclusive prefix for this thread
    int4 o;
    o.x = run; run += a.x; o.y = run; run += a.y; o.z = run; run += a.z; o.w = run; run += a.w;
    *(int4*)(offs + base) = o; *(int4*)(cursor + base) = o;
    o.x = run; run += b.x; o.y = run; run += b.y; o.z = run; run += b.z; o.w = run; run += b.w;
    *(int4*)(offs + base + 4) = o; *(int4*)(cursor + base + 4) = o;
    o.x = run; run += c.x; o.y = run; run += c.y; o.z = run; run += c.z; o.w = run; run += c.w;
    *(int4*)(offs + base + 8) = o; *(int4*)(cursor + base + 8) = o;
    o.x = run; run += d.x; o.y = run; run += d.y; o.z = run; run += d.z; o.w = run; run += d.w;
    *(int4*)(offs + base + 12) = o; *(int4*)(cursor + base + 12) = o;
}

__global__ void scan_kernel(const int* __restrict__ cntU, int* __restrict__ offsU, int* __restrict__ curU,
                            const int* __restrict__ cntTU, int* __restrict__ offsTU, int* __restrict__ curTU) {
    if (blockIdx.x == 0) scan_block(cntU, offsU, curU);
    else scan_block(cntTU, offsTU, curTU);
}

// ================= scatter: interactions by user (int2), targets by user (int4) =================
__global__ __launch_bounds__(256) void scatter_kernel(
        const int* __restrict__ user, const int* __restrict__ item,
        const float* __restrict__ rating, int* __restrict__ curU, int2* __restrict__ s_pack,
        const int* __restrict__ t_user, const int* __restrict__ t_item,
        const float* __restrict__ t_rating, int* __restrict__ curTU, int4* __restrict__ st_pack,
        int n, int nt) {
    int i = blockIdx.x * 256 + threadIdx.x;
    if (i < n) {
        int u = user[i];
        int pos = atomicAdd(&curU[u], 1);
        s_pack[pos] = make_int2(item[i], __float_as_int(rating[i]));
    }
    if (i < nt) {
        int tu = t_user[i];
        int pos = atomicAdd(&curTU[tu], 1);
        st_pack[pos] = make_int4(t_item[i], __float_as_int(t_rating[i]), i, 0);
    }
}

// ================= transpose W_enc [H0][NUM_ITEMS] f32 -> wtb8 [NUM_ITEMS][H0] fp8 (x64) =================
// 64it x 64h tiles; swizzled LDS: element (h, c) at tileh[h*64 + ((c + 4*(h>>2)) & 63)]
// write side: float4 stores, 2-way bank; read side: 2-way bank (was 4-way unswizzled).
__global__ __launch_bounds__(256) void transpose_kernel(const float* __restrict__ W_enc,
                                                        unsigned char* __restrict__ wtb8) {
    __shared__ float tileh[64 * 64];    // 16 KB -> 8 blocks/CU
    const int TBX = (NUM_ITEMS + 63) / 64;   // 782
    int b = blockIdx.x;
    int x0 = (b % TBX) * 64;        // item base
    int y0 = (b / TBX) * 64;        // h base
    int tid = threadIdx.x;
    int g = tid >> 4;               // 0..15 h-sub
    int m = tid & 15;               // item quad
    int it4 = x0 + m * 4;
#pragma unroll
    for (int p = 0; p < 4; ++p) {
        int hloc = p * 16 + g;
        if (it4 < NUM_ITEMS) {
            float4 v = *(const float4*)(W_enc + (size_t)(y0 + hloc) * NUM_ITEMS + it4);
            int cb = (m * 4 + ((hloc >> 2) << 2)) & 63;
            *(float4*)(tileh + hloc * 64 + cb) = v;
        }
    }
    __syncthreads();
    int i = tid >> 2;               // item 0..63
    int l = tid & 3;                // 16-element h chunk
    int it = x0 + i;
    if (it < NUM_ITEMS) {
        float f[16];
#pragma unroll
        for (int k = 0; k < 16; ++k) {
            int h = l * 16 + k;
            f[k] = tileh[h * 64 + ((i + ((h >> 2) << 2)) & 63)];
        }
        uint4 o;
        o.x = pkfp8_4(f[0] * FP8_SCALE, f[1] * FP8_SCALE, f[2] * FP8_SCALE, f[3] * FP8_SCALE);
        o.y = pkfp8_4(f[4] * FP8_SCALE, f[5] * FP8_SCALE, f[6] * FP8_SCALE, f[7] * FP8_SCALE);
        o.z = pkfp8_4(f[8] * FP8_SCALE, f[9] * FP8_SCALE, f[10] * FP8_SCALE, f[11] * FP8_SCALE);
        o.w = pkfp8_4(f[12] * FP8_SCALE, f[13] * FP8_SCALE, f[14] * FP8_SCALE, f[15] * FP8_SCALE);
        *(uint4*)(wtb8 + (size_t)it * H0 + y0 + l * 16) = o;
    }
}

// ================= streaming casts: W_dec -> fp8 ; W1/W2 -> bf16 =================
__global__ __launch_bounds__(256) void cast_kernel(const float* __restrict__ W_dec,
                                                   unsigned char* __restrict__ wdb8,
                                                   const float* __restrict__ W1, unsigned short* __restrict__ w1b,
                                                   const float* __restrict__ W2, unsigned short* __restrict__ w2b,
                                                   int DB) {
    int bid = blockIdx.x;
    int tid = threadIdx.x;
    if (bid < DB) {
        size_t idx = (size_t)bid * 4096 + tid * 16;
        float4 v0 = *(const float4*)(W_dec + idx);
        float4 v1 = *(const float4*)(W_dec + idx + 4);
        float4 v2 = *(const float4*)(W_dec + idx + 8);
        float4 v3 = *(const float4*)(W_dec + idx + 12);
        uint4 o;
        o.x = pkfp8_4(v0.x * FP8_SCALE, v0.y * FP8_SCALE, v0.z * FP8_SCALE, v0.w * FP8_SCALE);
        o.y = pkfp8_4(v1.x * FP8_SCALE, v1.y * FP8_SCALE, v1.z * FP8_SCALE, v1.w * FP8_SCALE);
        o.z = pkfp8_4(v2.x * FP8_SCALE, v2.y * FP8_SCALE, v2.z * FP8_SCALE, v2.w * FP8_SCALE);
        o.w = pkfp8_4(v3.x * FP8_SCALE, v3.y * FP8_SCALE, v3.z * FP8_SCALE, v3.w * FP8_SCALE);
        *(uint4*)(wdb8 + idx) = o;
    } else {
        int b2i = bid - DB;
        const float* src = (b2i < 64) ? W1 : W2;
        unsigned short* dst = (b2i < 64) ? w1b : w2b;
        int idx = (b2i & 63) * 2048 + tid * 8;
        float v[8];
        *(float4*)&v[0] = *(const float4*)(src + idx);
        *(float4*)&v[4] = *(const float4*)(src + idx + 4);
        *(uint4*)(dst + idx) = pack8(v);
    }
}

// ================= per-user segment sum + bias + tanh -> xb bf16 (depth-2 gather pipeline) =================
__global__ __launch_bounds__(256) void agg_kernel(const unsigned char* __restrict__ wtb8,
                                                  const int* __restrict__ offs,
                                                  const int* __restrict__ ends,
                                                  const int2* __restrict__ s_pack,
                                                  const float* __restrict__ b_enc,
                                                  unsigned short* __restrict__ xb) {
    __shared__ float red[3 * 512];
    int u = blockIdx.x;
    int tid = threadIdx.x;
    int g = tid >> 6, lane = tid & 63;
    float acc[8] = {};
    int j0 = offs[u], j1 = ends[u];
    int j = j0 + g;
    int2 c0 = (j < j1) ? s_pack[j] : make_int2(0, 0);
    int2 c1 = (j + 4 < j1) ? s_pack[j + 4] : make_int2(0, 0);
    while (j < j1) {
        bool has1 = (j + 4) < j1;
        // two gathers in flight
        uint2 v0 = ((const uint2*)(wtb8 + (size_t)c0.x * H0))[lane];
        uint2 v1 = has1 ? ((const uint2*)(wtb8 + (size_t)c1.x * H0))[lane] : make_uint2(0, 0);
        int jn = j + 8;
        int2 n0 = (jn < j1) ? s_pack[jn] : make_int2(0, 0);
        int2 n1 = (jn + 4 < j1) ? s_pack[jn + 4] : make_int2(0, 0);
        float r0 = __int_as_float(c0.y);
        float wf[8];
        fp8x4_to_f32(v0.x, wf);
        fp8x4_to_f32(v0.y, wf + 4);
#pragma unroll
        for (int e = 0; e < 8; ++e) acc[e] += wf[e] * r0;
        if (has1) {
            float r1 = __int_as_float(c1.y);
            fp8x4_to_f32(v1.x, wf);
            fp8x4_to_f32(v1.y, wf + 4);
#pragma unroll
            for (int e = 0; e < 8; ++e) acc[e] += wf[e] * r1;
        }
        c0 = n0; c1 = n1; j = jn;
    }
    if (g) {
        float4* rp = (float4*)red + (size_t)(g - 1) * 128 + lane * 2;
        rp[0] = make_float4(acc[0], acc[1], acc[2], acc[3]);
        rp[1] = make_float4(acc[4], acc[5], acc[6], acc[7]);
    }
    __syncthreads();
    if (g == 0) {
#pragma unroll
        for (int h = 0; h < 3; ++h) {
            const float* rp = red + h * 512 + lane * 8;
#pragma unroll
            for (int e = 0; e < 8; ++e) acc[e] += rp[e];
        }
        float4 b0 = ((const float4*)b_enc)[lane * 2];
        float4 b1 = ((const float4*)b_enc)[lane * 2 + 1];
        float o[8];
        o[0] = tanhf(acc[0] * FP8_INV + b0.x); o[1] = tanhf(acc[1] * FP8_INV + b0.y);
        o[2] = tanhf(acc[2] * FP8_INV + b0.z); o[3] = tanhf(acc[3] * FP8_INV + b0.w);
        o[4] = tanhf(acc[4] * FP8_INV + b1.x); o[5] = tanhf(acc[5] * FP8_INV + b1.y);
        o[6] = tanhf(acc[6] * FP8_INV + b1.z); o[7] = tanhf(acc[7] * FP8_INV + b1.w);
        ((uint4*)(xb + (size_t)u * H0))[lane] = pack8(o);
    }
}

// ================= bf16 MFMA GEMM, 128 x BN tile, tanh epilogue =================
template<int BN>
__global__ __launch_bounds__(256) void gemm_mfma(const unsigned short* __restrict__ A,
                                                 const unsigned short* __restrict__ B,
                                                 const float* __restrict__ bias,
                                                 unsigned short* __restrict__ C,
                                                 int Nn, int K) {
    constexpr int WN = BN / 32;
    constexpr int NCH = 8 + BN / 16;
    constexpr int PER = NCH / 4;
    __shared__ unsigned short Ash[128 * 32];
    __shared__ unsigned short Bsh[BN * 32];
    int tid = threadIdx.x;
    int wid = tid >> 6, lane = tid & 63;
    int wave_m = wid & 1, wave_n = wid >> 1;
    int quad = lane >> 4, l16 = lane & 15;
    int m0 = blockIdx.x * 128, n0 = blockIdx.y * BN;
    floatx4 acc[4][WN] = {};
    int srow = lane >> 2;
    int scol = (lane & 3) * 8;
    for (int k0 = 0; k0 < K; k0 += 32) {
#pragma unroll
        for (int i = 0; i < PER; ++i) {
            int c = wid * PER + i;
            if (c < 8) {
                const unsigned short* ga = A + (size_t)(m0 + c * 16 + srow) * K + k0 + scol;
                __builtin_amdgcn_global_load_lds(
                    (const __attribute__((address_space(1))) void*)ga,
                    (__attribute__((address_space(3))) void*)((__attribute__((address_space(3))) char*)Ash + c * 1024),
                    16, 0, 0);
            } else {
                const unsigned short* gb = B + (size_t)(n0 + (c - 8) * 16 + srow) * K + k0 + scol;
                __builtin_amdgcn_global_load_lds(
                    (const __attribute__((address_space(1))) void*)gb,
                    (__attribute__((address_space(3))) void*)((__attribute__((address_space(3))) char*)Bsh + (c - 8) * 1024),
                    16, 0, 0);
            }
        }
        __syncthreads();
        short8 af[4], bfr[WN];
#pragma unroll
        for (int i = 0; i < 4; ++i) {
            int ml = wave_m * 64 + i * 16 + l16;
            af[i] = ((const short8*)Ash)[ml * 4 + quad];
        }
#pragma unroll
        for (int j = 0; j < WN; ++j) {
            int nl = wave_n * (BN / 2) + j * 16 + l16;
            bfr[j] = ((const short8*)Bsh)[nl * 4 + quad];
        }
#pragma unroll
        for (int i = 0; i < 4; ++i)
#pragma unroll
            for (int j = 0; j < WN; ++j)
                acc[i][j] = __builtin_amdgcn_mfma_f32_16x16x32_bf16(af[i], bfr[j], acc[i][j], 0, 0, 0);
        __syncthreads();
    }
#pragma unroll
    for (int j = 0; j < WN; ++j) {
        int col = n0 + wave_n * (BN / 2) + j * 16 + l16;
        float bv = bias[col];
#pragma unroll
        for (int i = 0; i < 4; ++i) {
            int rowb = m0 + wave_m * 64 + i * 16 + quad * 4;
#pragma unroll
            for (int r = 0; r < 4; ++r)
                C[(size_t)(rowb + r) * Nn + col] = f2bf(tanhf(acc[i][j][r] + bv));
        }
    }
}

// ================= predict: one block per user, decoded row in regs, gather fp8 W rows =================
// NO same-address atomics: per-block partial -> partials[], reduced by loss_reduce.
__global__ __launch_bounds__(256) void predict_kernel(const unsigned short* __restrict__ dec_b,
                                                      const unsigned char* __restrict__ wdb8,
                                                      const float* __restrict__ b_dec,
                                                      const int* __restrict__ offs,
                                                      const int* __restrict__ ends,
                                                      const int4* __restrict__ st,
                                                      float* __restrict__ pred,
                                                      float* __restrict__ partials) {
    __shared__ float wsum[4];
    int u = blockIdx.x;
    int wid = threadIdx.x >> 6, lane = threadIdx.x & 63;
    int j0 = offs[u], j1 = ends[u];
    float sq = 0.f;
    if (j0 < j1) {
        // this user's decoded row: 8 bf16 per lane (coalesced, L1/L2-hot across the 4 waves)
        uint4 gv = ((const uint4*)(dec_b + (size_t)u * H0))[lane];
        float g[8];
        g[0] = bflo(gv.x); g[1] = bfhi(gv.x);
        g[2] = bflo(gv.y); g[3] = bfhi(gv.y);
        g[4] = bflo(gv.z); g[5] = bfhi(gv.z);
        g[6] = bflo(gv.w); g[7] = bfhi(gv.w);
        int j = j0 + wid;
        // depth-2 software pipeline on the target record AND the gathered row
        int4 tv = (j < j1) ? st[j] : make_int4(0, 0, 0, 0);
        uint2 wv = make_uint2(0, 0);
        if (j < j1) wv = ((const uint2*)(wdb8 + (size_t)tv.x * H0))[lane];
        while (j < j1) {
            int jn = j + 4;
            int4 tvn = make_int4(0, 0, 0, 0);
            uint2 wvn = make_uint2(0, 0);
            if (jn < j1) {
                tvn = st[jn];
                wvn = ((const uint2*)(wdb8 + (size_t)tvn.x * H0))[lane];
            }
            float wf[8];
            fp8x4_to_f32(wv.x, wf);
            fp8x4_to_f32(wv.y, wf + 4);
            float s = g[0] * wf[0] + g[1] * wf[1] + g[2] * wf[2] + g[3] * wf[3]
                    + g[4] * wf[4] + g[5] * wf[5] + g[6] * wf[6] + g[7] * wf[7];
#pragma unroll
            for (int off = 32; off; off >>= 1) s += __shfl_xor(s, off, 64);
            if (lane == 0) {
                float p = s * FP8_INV + b_dec[tv.x];
                pred[tv.z] = p;
                float d = p - __int_as_float(tv.y);
                sq += d * d;
            }
            j = jn; tv = tvn; wv = wvn;
        }
    }
    if (lane == 0) wsum[wid] = sq;
    __syncthreads();
    if (threadIdx.x == 0)
        partials[u] = wsum[0] + wsum[1] + wsum[2] + wsum[3];
}

__global__ void loss_reduce(const float* __restrict__ partials, float* __restrict__ out_loss,
                            int nPart, float invNT) {
    __shared__ float s[256];
    int t = threadIdx.x;
    float a = 0.f;
    const float4* p4 = (const float4*)partials;
    int n4 = nPart >> 2;
    for (int i = t; i < n4; i += 256) {
        float4 v = p4[i];
        a += v.x + v.y + v.z + v.w;
    }
    for (int i = (n4 << 2) + t; i < nPart; i += 256) a += partials[i];
    s[t] = a;
    __syncthreads();
    for (int off = 128; off; off >>= 1) {
        if (t < off) s[t] += s[t + off];
        __syncthreads();
    }
    if (t == 0) out_loss[0] = s[0] * invNT;
}

extern "C" void kernel_launch(void* const* d_in, const int* in_sizes, int n_in,
                              void* d_out, int out_size, void* d_ws, size_t ws_size,
                              hipStream_t stream) {
    const int* user = (const int*)d_in[0];
    const int* item = (const int*)d_in[1];
    const float* rating = (const float*)d_in[2];
    const int* t_user = (const int*)d_in[3];
    const int* t_item = (const int*)d_in[4];
    const float* t_rating = (const float*)d_in[5];
    const float* W_enc = (const float*)d_in[6];
    const float* b_enc = (const float*)d_in[7];
    const float* W1 = (const float*)d_in[8];
    const float* b1 = (const float*)d_in[9];
    const float* W2 = (const float*)d_in[10];
    const float* b2 = (const float*)d_in[11];
    const float* W_dec = (const float*)d_in[12];
    const float* b_dec = (const float*)d_in[13];
    const int N = in_sizes[0];
    const int NT = in_sizes[3];

    char* ws = (char*)d_ws;
    size_t off = 0;
    auto alloc = [&](size_t bytes) {
        void* p = ws + off;
        off = (off + bytes + 255) & ~(size_t)255;
        return p;
    };
    unsigned char* wtb8 = (unsigned char*)alloc((size_t)NUM_ITEMS * H0);        // 25.6 MB
    unsigned char* wdb8 = (unsigned char*)alloc((size_t)NUM_ITEMS * H0);        // 25.6 MB
    unsigned short* xb = (unsigned short*)alloc((size_t)NUM_USERS * H0 * 2);    // 16 MB
    unsigned short* enc_b = (unsigned short*)alloc((size_t)NUM_USERS * LAT * 2);// 8 MB
    unsigned short* dec_b = (unsigned short*)alloc((size_t)NUM_USERS * H0 * 2); // 16 MB
    unsigned short* w1b = (unsigned short*)alloc((size_t)LAT * H0 * 2);
    unsigned short* w2b = (unsigned short*)alloc((size_t)H0 * LAT * 2);
    int* cntU = (int*)alloc((size_t)NUM_USERS * 2 * 4);
    int* cntTU = cntU + NUM_USERS;
    int* offsU = (int*)alloc((size_t)NUM_USERS * 4);
    int* curU = (int*)alloc((size_t)NUM_USERS * 4);
    int* offsTU = (int*)alloc((size_t)NUM_USERS * 4);
    int* curTU = (int*)alloc((size_t)NUM_USERS * 4);
    int2* s_pack = (int2*)alloc((size_t)N * 8);
    int4* st_pack = (int4*)alloc((size_t)NT * 16);
    float* partials = (float*)alloc((size_t)NUM_USERS * 4);

    float* pred = (float*)d_out;
    float* loss = pred + NT;

    const int maxNNT = N > NT ? N : NT;
    const int SB = (maxNNT + 255) / 256;                 // 1024 scatter blocks
    const int TBX = (NUM_ITEMS + 63) / 64;               // 782
    const int TB = TBX * (H0 / 64);                      // 6256 transpose blocks
    const int DB = (NUM_ITEMS * H0) / 4096;              // 6250 W_dec cast blocks
    const int WB = 128;                                  // W1+W2 cast blocks

    hipMemsetAsync(cntU, 0, (size_t)NUM_USERS * 2 * 4, stream);
    count_kernel<<<(maxNNT + 1023) / 1024, 256, 0, stream>>>(user, cntU, t_user, cntTU, N, NT);
    scan_kernel<<<2, 1024, 0, stream>>>(cntU, offsU, curU, cntTU, offsTU, curTU);
    scatter_kernel<<<SB, 256, 0, stream>>>(user, item, rating, curU, s_pack,
                                           t_user, t_item, t_rating, curTU, st_pack, N, NT);
    transpose_kernel<<<TB, 256, 0, stream>>>(W_enc, wtb8);
    cast_kernel<<<DB + WB, 256, 0, stream>>>(W_dec, wdb8, W1, w1b, W2, w2b, DB);
    agg_kernel<<<NUM_USERS, 256, 0, stream>>>(wtb8, offsU, curU, s_pack, b_enc, xb);
    gemm_mfma<64><<<dim3(NUM_USERS / 128, LAT / 64), 256, 0, stream>>>(xb, w1b, b1, enc_b, LAT, H0);
    gemm_mfma<64><<<dim3(NUM_USERS / 128, H0 / 64), 256, 0, stream>>>(enc_b, w2b, b2, dec_b, H0, LAT);
    predict_kernel<<<NUM_USERS, 256, 0, stream>>>(dec_b, wdb8, b_dec, offsTU, curTU, st_pack, pred, partials);
    loss_reduce<<<1, 256, 0, stream>>>(partials, loss, NUM_USERS, 1.0f / NT);
}

// Round 5
// 416.177 us; speedup vs baseline: 1.0279x; 1.0279x over previous
//
#include <hip/hip_runtime.h>
#include <hip/hip_bf16.h>
#include <math.h>

#define NUM_ITEMS 50000
#define NUM_USERS 16384
#define H0 512
#define LAT 256
#define FP8_SCALE 64.0f   // weights ~±0.011 are subnormal in e4m3; x64 -> ~0.7 (3% rel err)
#define FP8_INV (1.0f / 64.0f)

typedef __attribute__((ext_vector_type(8))) short short8;
typedef __attribute__((ext_vector_type(4))) float floatx4;
typedef __attribute__((ext_vector_type(2))) float vf2;

__device__ __forceinline__ unsigned short f2bf(float f) {
    union { float f; unsigned i; } u; u.f = f;
    unsigned r = u.i + 0x7fff + ((u.i >> 16) & 1);   // RNE
    return (unsigned short)(r >> 16);
}
__device__ __forceinline__ float bfhi(unsigned v) {
    union { unsigned i; float f; } u; u.i = v & 0xffff0000u; return u.f;
}
__device__ __forceinline__ float bflo(unsigned v) {
    union { unsigned i; float f; } u; u.i = v << 16; return u.f;
}
__device__ __forceinline__ uint4 pack8(const float* v) {
    uint4 p;
    p.x = (unsigned)f2bf(v[0]) | ((unsigned)f2bf(v[1]) << 16);
    p.y = (unsigned)f2bf(v[2]) | ((unsigned)f2bf(v[3]) << 16);
    p.z = (unsigned)f2bf(v[4]) | ((unsigned)f2bf(v[5]) << 16);
    p.w = (unsigned)f2bf(v[6]) | ((unsigned)f2bf(v[7]) << 16);
    return p;
}
// pack 4 floats -> 4 fp8 e4m3 (OCP on gfx950)
__device__ __forceinline__ unsigned pkfp8_4(float a, float b, float c, float d) {
    int v = __builtin_amdgcn_cvt_pk_fp8_f32(a, b, 0, false);
    v = __builtin_amdgcn_cvt_pk_fp8_f32(c, d, v, true);
    return (unsigned)v;
}
__device__ __forceinline__ void fp8x4_to_f32(unsigned v, float* o) {
    vf2 lo = __builtin_amdgcn_cvt_pk_f32_fp8((int)v, false);
    vf2 hi = __builtin_amdgcn_cvt_pk_f32_fp8((int)v, true);
    o[0] = lo.x; o[1] = lo.y; o[2] = hi.x; o[3] = hi.y;
}
__device__ __forceinline__ void unpbf8(uint4 q, float* o) {
    o[0] = bflo(q.x); o[1] = bfhi(q.x);
    o[2] = bflo(q.y); o[3] = bfhi(q.y);
    o[4] = bflo(q.z); o[5] = bfhi(q.z);
    o[6] = bflo(q.w); o[7] = bfhi(q.w);
}

// ================= count: users (interactions) + users (targets) =================
__global__ __launch_bounds__(256) void count_kernel(const int* __restrict__ user, int* __restrict__ cntU,
                                                    const int* __restrict__ t_user, int* __restrict__ cntTU,
                                                    int n, int nt) {
    int i = (blockIdx.x * blockDim.x + threadIdx.x) * 4;
    if (i + 3 < n) {
        int4 u = *(const int4*)(user + i);
        atomicAdd(&cntU[u.x], 1); atomicAdd(&cntU[u.y], 1);
        atomicAdd(&cntU[u.z], 1); atomicAdd(&cntU[u.w], 1);
    } else {
        for (int k = i; k < n; ++k) atomicAdd(&cntU[user[k]], 1);
    }
    if (i + 3 < nt) {
        int4 t = *(const int4*)(t_user + i);
        atomicAdd(&cntTU[t.x], 1); atomicAdd(&cntTU[t.y], 1);
        atomicAdd(&cntTU[t.z], 1); atomicAdd(&cntTU[t.w], 1);
    } else {
        for (int k = i; k < nt; ++k) atomicAdd(&cntTU[t_user[k]], 1);
    }
}

// ================= dual exclusive scan (shfl-based, 2 barriers) =================
__device__ void scan_block(const int* __restrict__ cnt, int* __restrict__ offs,
                           int* __restrict__ cursor) {
    // 1024 threads, 16 elements each (16384 total)
    __shared__ int wsum_s[16];
    int t = threadIdx.x;
    int lane = t & 63, wid = t >> 6;
    int base = t * 16;
    int4 a = *(const int4*)(cnt + base);
    int4 b = *(const int4*)(cnt + base + 4);
    int4 c = *(const int4*)(cnt + base + 8);
    int4 d = *(const int4*)(cnt + base + 12);
    int s = a.x + a.y + a.z + a.w + b.x + b.y + b.z + b.w
          + c.x + c.y + c.z + c.w + d.x + d.y + d.z + d.w;
    // inclusive wave scan of per-thread sums
    int sc = s;
#pragma unroll
    for (int off = 1; off < 64; off <<= 1) {
        int v = __shfl_up(sc, off, 64);
        if (lane >= off) sc += v;
    }
    if (lane == 63) wsum_s[wid] = sc;
    __syncthreads();
    if (t < 16) {
        int w = wsum_s[t];
        int wsc = w;
#pragma unroll
        for (int off = 1; off < 16; off <<= 1) {
            int v = __shfl_up(wsc, off, 64);
            if (t >= off) wsc += v;
        }
        wsum_s[t] = wsc - w;    // exclusive wave prefix
    }
    __syncthreads();
    int run = wsum_s[wid] + (sc - s);   // global exclusive prefix for this thread
    int4 o;
    o.x = run; run += a.x; o.y = run; run += a.y; o.z = run; run += a.z; o.w = run; run += a.w;
    *(int4*)(offs + base) = o; *(int4*)(cursor + base) = o;
    o.x = run; run += b.x; o.y = run; run += b.y; o.z = run; run += b.z; o.w = run; run += b.w;
    *(int4*)(offs + base + 4) = o; *(int4*)(cursor + base + 4) = o;
    o.x = run; run += c.x; o.y = run; run += c.y; o.z = run; run += c.z; o.w = run; run += c.w;
    *(int4*)(offs + base + 8) = o; *(int4*)(cursor + base + 8) = o;
    o.x = run; run += d.x; o.y = run; run += d.y; o.z = run; run += d.z; o.w = run; run += d.w;
    *(int4*)(offs + base + 12) = o; *(int4*)(cursor + base + 12) = o;
}

__global__ void scan_kernel(const int* __restrict__ cntU, int* __restrict__ offsU, int* __restrict__ curU,
                            const int* __restrict__ cntTU, int* __restrict__ offsTU, int* __restrict__ curTU) {
    if (blockIdx.x == 0) scan_block(cntU, offsU, curU);
    else scan_block(cntTU, offsTU, curTU);
}

// ================= scatter: interactions by user (int2), targets by user (int4) =================
__global__ __launch_bounds__(256) void scatter_kernel(
        const int* __restrict__ user, const int* __restrict__ item,
        const float* __restrict__ rating, int* __restrict__ curU, int2* __restrict__ s_pack,
        const int* __restrict__ t_user, const int* __restrict__ t_item,
        const float* __restrict__ t_rating, int* __restrict__ curTU, int4* __restrict__ st_pack,
        int n, int nt) {
    int i = blockIdx.x * 256 + threadIdx.x;
    if (i < n) {
        int u = user[i];
        int pos = atomicAdd(&curU[u], 1);
        s_pack[pos] = make_int2(item[i], __float_as_int(rating[i]));
    }
    if (i < nt) {
        int tu = t_user[i];
        int pos = atomicAdd(&curTU[tu], 1);
        st_pack[pos] = make_int4(t_item[i], __float_as_int(t_rating[i]), i, 0);
    }
}

// ================= transpose W_enc [H0][NUM_ITEMS] f32 -> wtb8 [NUM_ITEMS][H0] fp8 (x64) =================
// 128it x 64h tiles: each wave reads 2 rows x 512B contiguous (32 lanes x float4) -> long DRAM runs.
// LDS [64][128] f32 = 32KB (5 blocks/CU). Read side: bank = item%32, 2 h per wave -> 2-way (free).
__global__ __launch_bounds__(256) void transpose_kernel(const float* __restrict__ W_enc,
                                                        unsigned char* __restrict__ wtb8) {
    __shared__ float tileh[64 * 128];    // 32 KB
    const int TBX = (NUM_ITEMS + 127) / 128;   // 391
    int b = blockIdx.x;
    int x0 = (b % TBX) * 128;       // item base
    int y0 = (b / TBX) * 64;        // h base
    int tid = threadIdx.x;
    int g = tid >> 5;               // 0..7 h-sub
    int m = tid & 31;               // item quad
    int it4 = x0 + m * 4;
#pragma unroll
    for (int p = 0; p < 8; ++p) {
        int hloc = p * 8 + g;
        if (it4 < NUM_ITEMS) {
            float4 v = *(const float4*)(W_enc + (size_t)(y0 + hloc) * NUM_ITEMS + it4);
            *(float4*)(tileh + hloc * 128 + m * 4) = v;
        }
    }
    __syncthreads();
    int i = tid >> 1;               // item 0..127
    int l = tid & 1;                // h-half (32 each)
    int it = x0 + i;
    if (it < NUM_ITEMS) {
        float f[32];
#pragma unroll
        for (int k = 0; k < 32; ++k)
            f[k] = tileh[(l * 32 + k) * 128 + i];
        uint4 o0, o1;
        o0.x = pkfp8_4(f[0] * FP8_SCALE, f[1] * FP8_SCALE, f[2] * FP8_SCALE, f[3] * FP8_SCALE);
        o0.y = pkfp8_4(f[4] * FP8_SCALE, f[5] * FP8_SCALE, f[6] * FP8_SCALE, f[7] * FP8_SCALE);
        o0.z = pkfp8_4(f[8] * FP8_SCALE, f[9] * FP8_SCALE, f[10] * FP8_SCALE, f[11] * FP8_SCALE);
        o0.w = pkfp8_4(f[12] * FP8_SCALE, f[13] * FP8_SCALE, f[14] * FP8_SCALE, f[15] * FP8_SCALE);
        o1.x = pkfp8_4(f[16] * FP8_SCALE, f[17] * FP8_SCALE, f[18] * FP8_SCALE, f[19] * FP8_SCALE);
        o1.y = pkfp8_4(f[20] * FP8_SCALE, f[21] * FP8_SCALE, f[22] * FP8_SCALE, f[23] * FP8_SCALE);
        o1.z = pkfp8_4(f[24] * FP8_SCALE, f[25] * FP8_SCALE, f[26] * FP8_SCALE, f[27] * FP8_SCALE);
        o1.w = pkfp8_4(f[28] * FP8_SCALE, f[29] * FP8_SCALE, f[30] * FP8_SCALE, f[31] * FP8_SCALE);
        unsigned char* dst = wtb8 + (size_t)it * H0 + y0 + l * 32;
        *(uint4*)dst = o0;
        *(uint4*)(dst + 16) = o1;
    }
}

// ================= streaming casts: W_dec -> fp8 ; W1/W2 -> bf16 =================
__global__ __launch_bounds__(256) void cast_kernel(const float* __restrict__ W_dec,
                                                   unsigned char* __restrict__ wdb8,
                                                   const float* __restrict__ W1, unsigned short* __restrict__ w1b,
                                                   const float* __restrict__ W2, unsigned short* __restrict__ w2b,
                                                   int DB) {
    int bid = blockIdx.x;
    int tid = threadIdx.x;
    if (bid < DB) {
        size_t idx = (size_t)bid * 4096 + tid * 16;
        float4 v0 = *(const float4*)(W_dec + idx);
        float4 v1 = *(const float4*)(W_dec + idx + 4);
        float4 v2 = *(const float4*)(W_dec + idx + 8);
        float4 v3 = *(const float4*)(W_dec + idx + 12);
        uint4 o;
        o.x = pkfp8_4(v0.x * FP8_SCALE, v0.y * FP8_SCALE, v0.z * FP8_SCALE, v0.w * FP8_SCALE);
        o.y = pkfp8_4(v1.x * FP8_SCALE, v1.y * FP8_SCALE, v1.z * FP8_SCALE, v1.w * FP8_SCALE);
        o.z = pkfp8_4(v2.x * FP8_SCALE, v2.y * FP8_SCALE, v2.z * FP8_SCALE, v2.w * FP8_SCALE);
        o.w = pkfp8_4(v3.x * FP8_SCALE, v3.y * FP8_SCALE, v3.z * FP8_SCALE, v3.w * FP8_SCALE);
        *(uint4*)(wdb8 + idx) = o;
    } else {
        int b2i = bid - DB;
        const float* src = (b2i < 64) ? W1 : W2;
        unsigned short* dst = (b2i < 64) ? w1b : w2b;
        int idx = (b2i & 63) * 2048 + tid * 8;
        float v[8];
        *(float4*)&v[0] = *(const float4*)(src + idx);
        *(float4*)&v[4] = *(const float4*)(src + idx + 4);
        *(uint4*)(dst + idx) = pack8(v);
    }
}

// ================= per-user segment sum + bias + tanh -> xb bf16 (depth-2 gather pipeline) =================
__global__ __launch_bounds__(256) void agg_kernel(const unsigned char* __restrict__ wtb8,
                                                  const int* __restrict__ offs,
                                                  const int* __restrict__ ends,
                                                  const int2* __restrict__ s_pack,
                                                  const float* __restrict__ b_enc,
                                                  unsigned short* __restrict__ xb) {
    __shared__ float red[3 * 512];
    int u = blockIdx.x;
    int tid = threadIdx.x;
    int g = tid >> 6, lane = tid & 63;
    float acc[8] = {};
    int j0 = offs[u], j1 = ends[u];
    int j = j0 + g;
    int2 c0 = (j < j1) ? s_pack[j] : make_int2(0, 0);
    int2 c1 = (j + 4 < j1) ? s_pack[j + 4] : make_int2(0, 0);
    while (j < j1) {
        bool has1 = (j + 4) < j1;
        // two gathers in flight
        uint2 v0 = ((const uint2*)(wtb8 + (size_t)c0.x * H0))[lane];
        uint2 v1 = has1 ? ((const uint2*)(wtb8 + (size_t)c1.x * H0))[lane] : make_uint2(0, 0);
        int jn = j + 8;
        int2 n0 = (jn < j1) ? s_pack[jn] : make_int2(0, 0);
        int2 n1 = (jn + 4 < j1) ? s_pack[jn + 4] : make_int2(0, 0);
        float r0 = __int_as_float(c0.y);
        float wf[8];
        fp8x4_to_f32(v0.x, wf);
        fp8x4_to_f32(v0.y, wf + 4);
#pragma unroll
        for (int e = 0; e < 8; ++e) acc[e] += wf[e] * r0;
        if (has1) {
            float r1 = __int_as_float(c1.y);
            fp8x4_to_f32(v1.x, wf);
            fp8x4_to_f32(v1.y, wf + 4);
#pragma unroll
            for (int e = 0; e < 8; ++e) acc[e] += wf[e] * r1;
        }
        c0 = n0; c1 = n1; j = jn;
    }
    if (g) {
        float4* rp = (float4*)red + (size_t)(g - 1) * 128 + lane * 2;
        rp[0] = make_float4(acc[0], acc[1], acc[2], acc[3]);
        rp[1] = make_float4(acc[4], acc[5], acc[6], acc[7]);
    }
    __syncthreads();
    if (g == 0) {
#pragma unroll
        for (int h = 0; h < 3; ++h) {
            const float* rp = red + h * 512 + lane * 8;
#pragma unroll
            for (int e = 0; e < 8; ++e) acc[e] += rp[e];
        }
        float4 b0 = ((const float4*)b_enc)[lane * 2];
        float4 b1 = ((const float4*)b_enc)[lane * 2 + 1];
        float o[8];
        o[0] = tanhf(acc[0] * FP8_INV + b0.x); o[1] = tanhf(acc[1] * FP8_INV + b0.y);
        o[2] = tanhf(acc[2] * FP8_INV + b0.z); o[3] = tanhf(acc[3] * FP8_INV + b0.w);
        o[4] = tanhf(acc[4] * FP8_INV + b1.x); o[5] = tanhf(acc[5] * FP8_INV + b1.y);
        o[6] = tanhf(acc[6] * FP8_INV + b1.z); o[7] = tanhf(acc[7] * FP8_INV + b1.w);
        ((uint4*)(xb + (size_t)u * H0))[lane] = pack8(o);
    }
}

// ================= bf16 MFMA GEMM, 128 x BN tile, tanh epilogue =================
template<int BN>
__global__ __launch_bounds__(256) void gemm_mfma(const unsigned short* __restrict__ A,
                                                 const unsigned short* __restrict__ B,
                                                 const float* __restrict__ bias,
                                                 unsigned short* __restrict__ C,
                                                 int Nn, int K) {
    constexpr int WN = BN / 32;
    constexpr int NCH = 8 + BN / 16;
    constexpr int PER = NCH / 4;
    __shared__ unsigned short Ash[128 * 32];
    __shared__ unsigned short Bsh[BN * 32];
    int tid = threadIdx.x;
    int wid = tid >> 6, lane = tid & 63;
    int wave_m = wid & 1, wave_n = wid >> 1;
    int quad = lane >> 4, l16 = lane & 15;
    int m0 = blockIdx.x * 128, n0 = blockIdx.y * BN;
    floatx4 acc[4][WN] = {};
    int srow = lane >> 2;
    int scol = (lane & 3) * 8;
    for (int k0 = 0; k0 < K; k0 += 32) {
#pragma unroll
        for (int i = 0; i < PER; ++i) {
            int c = wid * PER + i;
            if (c < 8) {
                const unsigned short* ga = A + (size_t)(m0 + c * 16 + srow) * K + k0 + scol;
                __builtin_amdgcn_global_load_lds(
                    (const __attribute__((address_space(1))) void*)ga,
                    (__attribute__((address_space(3))) void*)((__attribute__((address_space(3))) char*)Ash + c * 1024),
                    16, 0, 0);
            } else {
                const unsigned short* gb = B + (size_t)(n0 + (c - 8) * 16 + srow) * K + k0 + scol;
                __builtin_amdgcn_global_load_lds(
                    (const __attribute__((address_space(1))) void*)gb,
                    (__attribute__((address_space(3))) void*)((__attribute__((address_space(3))) char*)Bsh + (c - 8) * 1024),
                    16, 0, 0);
            }
        }
        __syncthreads();
        short8 af[4], bfr[WN];
#pragma unroll
        for (int i = 0; i < 4; ++i) {
            int ml = wave_m * 64 + i * 16 + l16;
            af[i] = ((const short8*)Ash)[ml * 4 + quad];
        }
#pragma unroll
        for (int j = 0; j < WN; ++j) {
            int nl = wave_n * (BN / 2) + j * 16 + l16;
            bfr[j] = ((const short8*)Bsh)[nl * 4 + quad];
        }
#pragma unroll
        for (int i = 0; i < 4; ++i)
#pragma unroll
            for (int j = 0; j < WN; ++j)
                acc[i][j] = __builtin_amdgcn_mfma_f32_16x16x32_bf16(af[i], bfr[j], acc[i][j], 0, 0, 0);
        __syncthreads();
    }
#pragma unroll
    for (int j = 0; j < WN; ++j) {
        int col = n0 + wave_n * (BN / 2) + j * 16 + l16;
        float bv = bias[col];
#pragma unroll
        for (int i = 0; i < 4; ++i) {
            int rowb = m0 + wave_m * 64 + i * 16 + quad * 4;
#pragma unroll
            for (int r = 0; r < 4; ++r)
                C[(size_t)(rowb + r) * Nn + col] = f2bf(tanhf(acc[i][j][r] + bv));
        }
    }
}

// ================= predict: one block per user; 16-lane groups -> 4 targets/wave in flight =================
// lane = grp*16 + sl: group grp handles target (base+grp), lane-slice sl covers h = sl*32..sl*32+31.
// NO same-address atomics: per-block partial -> partials[], reduced by loss_reduce.
__global__ __launch_bounds__(256) void predict_kernel(const unsigned short* __restrict__ dec_b,
                                                      const unsigned char* __restrict__ wdb8,
                                                      const float* __restrict__ b_dec,
                                                      const int* __restrict__ offs,
                                                      const int* __restrict__ ends,
                                                      const int4* __restrict__ st,
                                                      float* __restrict__ pred,
                                                      float* __restrict__ partials) {
    __shared__ float wsum[4];
    int u = blockIdx.x;
    int wid = threadIdx.x >> 6, lane = threadIdx.x & 63;
    int grp = lane >> 4, sl = lane & 15;
    int j0 = offs[u], j1 = ends[u];
    float sq = 0.f;
    if (j0 < j1) {
        // this user's decoded row slice: 32 bf16 (elements sl*32..+31)
        const uint4* gp = (const uint4*)(dec_b + (size_t)u * H0) + sl * 4;
        float g[32];
        unpbf8(gp[0], g);
        unpbf8(gp[1], g + 8);
        unpbf8(gp[2], g + 16);
        unpbf8(gp[3], g + 24);
        for (int base = j0 + wid * 4; base < j1; base += 16) {
            int idx = base + grp;
            bool act = idx < j1;
            int4 tv = st[min(idx, j1 - 1)];
            const unsigned char* wr = wdb8 + (size_t)tv.x * H0 + sl * 32;
            uint4 wa = *(const uint4*)wr;
            uint4 wb = *(const uint4*)(wr + 16);
            unsigned wu[8] = {wa.x, wa.y, wa.z, wa.w, wb.x, wb.y, wb.z, wb.w};
            float s = 0.f;
#pragma unroll
            for (int q = 0; q < 8; ++q) {
                float wf[4];
                fp8x4_to_f32(wu[q], wf);
                s += g[q * 4 + 0] * wf[0] + g[q * 4 + 1] * wf[1]
                   + g[q * 4 + 2] * wf[2] + g[q * 4 + 3] * wf[3];
            }
            s += __shfl_xor(s, 1, 64);
            s += __shfl_xor(s, 2, 64);
            s += __shfl_xor(s, 4, 64);
            s += __shfl_xor(s, 8, 64);
            if (act && sl == 0) {
                float p = s * FP8_INV + b_dec[tv.x];
                pred[tv.z] = p;
                float d = p - __int_as_float(tv.y);
                sq += d * d;
            }
        }
    }
    // combine the 4 group-leader lanes (sl==0) of this wave
    sq += __shfl_xor(sq, 16, 64);
    sq += __shfl_xor(sq, 32, 64);
    if (lane == 0) wsum[wid] = sq;
    __syncthreads();
    if (threadIdx.x == 0)
        partials[u] = wsum[0] + wsum[1] + wsum[2] + wsum[3];
}

__global__ void loss_reduce(const float* __restrict__ partials, float* __restrict__ out_loss,
                            int nPart, float invNT) {
    __shared__ float s[256];
    int t = threadIdx.x;
    float a = 0.f;
    const float4* p4 = (const float4*)partials;
    int n4 = nPart >> 2;
    for (int i = t; i < n4; i += 256) {
        float4 v = p4[i];
        a += v.x + v.y + v.z + v.w;
    }
    for (int i = (n4 << 2) + t; i < nPart; i += 256) a += partials[i];
    s[t] = a;
    __syncthreads();
    for (int off = 128; off; off >>= 1) {
        if (t < off) s[t] += s[t + off];
        __syncthreads();
    }
    if (t == 0) out_loss[0] = s[0] * invNT;
}

extern "C" void kernel_launch(void* const* d_in, const int* in_sizes, int n_in,
                              void* d_out, int out_size, void* d_ws, size_t ws_size,
                              hipStream_t stream) {
    const int* user = (const int*)d_in[0];
    const int* item = (const int*)d_in[1];
    const float* rating = (const float*)d_in[2];
    const int* t_user = (const int*)d_in[3];
    const int* t_item = (const int*)d_in[4];
    const float* t_rating = (const float*)d_in[5];
    const float* W_enc = (const float*)d_in[6];
    const float* b_enc = (const float*)d_in[7];
    const float* W1 = (const float*)d_in[8];
    const float* b1 = (const float*)d_in[9];
    const float* W2 = (const float*)d_in[10];
    const float* b2 = (const float*)d_in[11];
    const float* W_dec = (const float*)d_in[12];
    const float* b_dec = (const float*)d_in[13];
    const int N = in_sizes[0];
    const int NT = in_sizes[3];

    char* ws = (char*)d_ws;
    size_t off = 0;
    auto alloc = [&](size_t bytes) {
        void* p = ws + off;
        off = (off + bytes + 255) & ~(size_t)255;
        return p;
    };
    unsigned char* wtb8 = (unsigned char*)alloc((size_t)NUM_ITEMS * H0);        // 25.6 MB
    unsigned char* wdb8 = (unsigned char*)alloc((size_t)NUM_ITEMS * H0);        // 25.6 MB
    unsigned short* xb = (unsigned short*)alloc((size_t)NUM_USERS * H0 * 2);    // 16 MB
    unsigned short* enc_b = (unsigned short*)alloc((size_t)NUM_USERS * LAT * 2);// 8 MB
    unsigned short* dec_b = (unsigned short*)alloc((size_t)NUM_USERS * H0 * 2); // 16 MB
    unsigned short* w1b = (unsigned short*)alloc((size_t)LAT * H0 * 2);
    unsigned short* w2b = (unsigned short*)alloc((size_t)H0 * LAT * 2);
    int* cntU = (int*)alloc((size_t)NUM_USERS * 2 * 4);
    int* cntTU = cntU + NUM_USERS;
    int* offsU = (int*)alloc((size_t)NUM_USERS * 4);
    int* curU = (int*)alloc((size_t)NUM_USERS * 4);
    int* offsTU = (int*)alloc((size_t)NUM_USERS * 4);
    int* curTU = (int*)alloc((size_t)NUM_USERS * 4);
    int2* s_pack = (int2*)alloc((size_t)N * 8);
    int4* st_pack = (int4*)alloc((size_t)NT * 16);
    float* partials = (float*)alloc((size_t)NUM_USERS * 4);

    float* pred = (float*)d_out;
    float* loss = pred + NT;

    const int maxNNT = N > NT ? N : NT;
    const int SB = (maxNNT + 255) / 256;                 // 1024 scatter blocks
    const int TBX = (NUM_ITEMS + 127) / 128;             // 391
    const int TB = TBX * (H0 / 64);                      // 3128 transpose blocks
    const int DB = (NUM_ITEMS * H0) / 4096;              // 6250 W_dec cast blocks
    const int WB = 128;                                  // W1+W2 cast blocks

    hipMemsetAsync(cntU, 0, (size_t)NUM_USERS * 2 * 4, stream);
    count_kernel<<<(maxNNT + 1023) / 1024, 256, 0, stream>>>(user, cntU, t_user, cntTU, N, NT);
    scan_kernel<<<2, 1024, 0, stream>>>(cntU, offsU, curU, cntTU, offsTU, curTU);
    scatter_kernel<<<SB, 256, 0, stream>>>(user, item, rating, curU, s_pack,
                                           t_user, t_item, t_rating, curTU, st_pack, N, NT);
    transpose_kernel<<<TB, 256, 0, stream>>>(W_enc, wtb8);
    cast_kernel<<<DB + WB, 256, 0, stream>>>(W_dec, wdb8, W1, w1b, W2, w2b, DB);
    agg_kernel<<<NUM_USERS, 256, 0, stream>>>(wtb8, offsU, curU, s_pack, b_enc, xb);
    gemm_mfma<64><<<dim3(NUM_USERS / 128, LAT / 64), 256, 0, stream>>>(xb, w1b, b1, enc_b, LAT, H0);
    gemm_mfma<64><<<dim3(NUM_USERS / 128, H0 / 64), 256, 0, stream>>>(enc_b, w2b, b2, dec_b, H0, LAT);
    predict_kernel<<<NUM_USERS, 256, 0, stream>>>(dec_b, wdb8, b_dec, offsTU, curTU, st_pack, pred, partials);
    loss_reduce<<<1, 256, 0, stream>>>(partials, loss, NUM_USERS, 1.0f / NT);
}

// Round 6
// 400.256 us; speedup vs baseline: 1.0688x; 1.0398x over previous
//
#include <hip/hip_runtime.h>
#include <hip/hip_bf16.h>
#include <math.h>

#define NUM_ITEMS 50000
#define NUM_USERS 16384
#define H0 512
#define LAT 256
#define FP8_SCALE 64.0f   // weights ~±0.011 are subnormal in e4m3; x64 -> ~0.7 (3% rel err)
#define FP8_INV (1.0f / 64.0f)

typedef __attribute__((ext_vector_type(8))) short short8;
typedef __attribute__((ext_vector_type(4))) float floatx4;
typedef __attribute__((ext_vector_type(2))) float vf2;

__device__ __forceinline__ unsigned short f2bf(float f) {
    union { float f; unsigned i; } u; u.f = f;
    unsigned r = u.i + 0x7fff + ((u.i >> 16) & 1);   // RNE
    return (unsigned short)(r >> 16);
}
__device__ __forceinline__ float bfhi(unsigned v) {
    union { unsigned i; float f; } u; u.i = v & 0xffff0000u; return u.f;
}
__device__ __forceinline__ float bflo(unsigned v) {
    union { unsigned i; float f; } u; u.i = v << 16; return u.f;
}
__device__ __forceinline__ uint4 pack8(const float* v) {
    uint4 p;
    p.x = (unsigned)f2bf(v[0]) | ((unsigned)f2bf(v[1]) << 16);
    p.y = (unsigned)f2bf(v[2]) | ((unsigned)f2bf(v[3]) << 16);
    p.z = (unsigned)f2bf(v[4]) | ((unsigned)f2bf(v[5]) << 16);
    p.w = (unsigned)f2bf(v[6]) | ((unsigned)f2bf(v[7]) << 16);
    return p;
}
// pack 4 floats -> 4 fp8 e4m3 (OCP on gfx950)
__device__ __forceinline__ unsigned pkfp8_4(float a, float b, float c, float d) {
    int v = __builtin_amdgcn_cvt_pk_fp8_f32(a, b, 0, false);
    v = __builtin_amdgcn_cvt_pk_fp8_f32(c, d, v, true);
    return (unsigned)v;
}
__device__ __forceinline__ void fp8x4_to_f32(unsigned v, float* o) {
    vf2 lo = __builtin_amdgcn_cvt_pk_f32_fp8((int)v, false);
    vf2 hi = __builtin_amdgcn_cvt_pk_f32_fp8((int)v, true);
    o[0] = lo.x; o[1] = lo.y; o[2] = hi.x; o[3] = hi.y;
}
__device__ __forceinline__ void unpbf8(uint4 q, float* o) {
    o[0] = bflo(q.x); o[1] = bfhi(q.x);
    o[2] = bflo(q.y); o[3] = bfhi(q.y);
    o[4] = bflo(q.z); o[5] = bfhi(q.z);
    o[6] = bflo(q.w); o[7] = bfhi(q.w);
}

// ================= count: users (interactions) + users (targets) =================
__global__ __launch_bounds__(256) void count_kernel(const int* __restrict__ user, int* __restrict__ cntU,
                                                    const int* __restrict__ t_user, int* __restrict__ cntTU,
                                                    int n, int nt) {
    int i = (blockIdx.x * blockDim.x + threadIdx.x) * 4;
    if (i + 3 < n) {
        int4 u = *(const int4*)(user + i);
        atomicAdd(&cntU[u.x], 1); atomicAdd(&cntU[u.y], 1);
        atomicAdd(&cntU[u.z], 1); atomicAdd(&cntU[u.w], 1);
    } else {
        for (int k = i; k < n; ++k) atomicAdd(&cntU[user[k]], 1);
    }
    if (i + 3 < nt) {
        int4 t = *(const int4*)(t_user + i);
        atomicAdd(&cntTU[t.x], 1); atomicAdd(&cntTU[t.y], 1);
        atomicAdd(&cntTU[t.z], 1); atomicAdd(&cntTU[t.w], 1);
    } else {
        for (int k = i; k < nt; ++k) atomicAdd(&cntTU[t_user[k]], 1);
    }
}

// ================= dual exclusive scan (shfl-based, 2 barriers) =================
__device__ void scan_block(const int* __restrict__ cnt, int* __restrict__ offs,
                           int* __restrict__ cursor) {
    // 1024 threads, 16 elements each (16384 total)
    __shared__ int wsum_s[16];
    int t = threadIdx.x;
    int lane = t & 63, wid = t >> 6;
    int base = t * 16;
    int4 a = *(const int4*)(cnt + base);
    int4 b = *(const int4*)(cnt + base + 4);
    int4 c = *(const int4*)(cnt + base + 8);
    int4 d = *(const int4*)(cnt + base + 12);
    int s = a.x + a.y + a.z + a.w + b.x + b.y + b.z + b.w
          + c.x + c.y + c.z + c.w + d.x + d.y + d.z + d.w;
    int sc = s;
#pragma unroll
    for (int off = 1; off < 64; off <<= 1) {
        int v = __shfl_up(sc, off, 64);
        if (lane >= off) sc += v;
    }
    if (lane == 63) wsum_s[wid] = sc;
    __syncthreads();
    if (t < 16) {
        int w = wsum_s[t];
        int wsc = w;
#pragma unroll
        for (int off = 1; off < 16; off <<= 1) {
            int v = __shfl_up(wsc, off, 64);
            if (t >= off) wsc += v;
        }
        wsum_s[t] = wsc - w;    // exclusive wave prefix
    }
    __syncthreads();
    int run = wsum_s[wid] + (sc - s);   // global exclusive prefix for this thread
    int4 o;
    o.x = run; run += a.x; o.y = run; run += a.y; o.z = run; run += a.z; o.w = run; run += a.w;
    *(int4*)(offs + base) = o; *(int4*)(cursor + base) = o;
    o.x = run; run += b.x; o.y = run; run += b.y; o.z = run; run += b.z; o.w = run; run += b.w;
    *(int4*)(offs + base + 4) = o; *(int4*)(cursor + base + 4) = o;
    o.x = run; run += c.x; o.y = run; run += c.y; o.z = run; run += c.z; o.w = run; run += c.w;
    *(int4*)(offs + base + 8) = o; *(int4*)(cursor + base + 8) = o;
    o.x = run; run += d.x; o.y = run; run += d.y; o.z = run; run += d.z; o.w = run; run += d.w;
    *(int4*)(offs + base + 12) = o; *(int4*)(cursor + base + 12) = o;
}

__global__ void scan_kernel(const int* __restrict__ cntU, int* __restrict__ offsU, int* __restrict__ curU,
                            const int* __restrict__ cntTU, int* __restrict__ offsTU, int* __restrict__ curTU) {
    if (blockIdx.x == 0) scan_block(cntU, offsU, curU);
    else scan_block(cntTU, offsTU, curTU);
}

// ================= mega kernel: scatter | transpose W_enc->fp8 | W_dec->fp8 | W1/W2->bf16 =================
// Fused for profile visibility (r3<->r4 proved fusion is perf-neutral). 32 KB LDS -> 5 blocks/CU.
__global__ __launch_bounds__(256) void mega_kernel(
        const int* __restrict__ user, const int* __restrict__ item,
        const float* __restrict__ rating, int* __restrict__ curU, int2* __restrict__ s_pack,
        const int* __restrict__ t_user, const int* __restrict__ t_item,
        const float* __restrict__ t_rating, int* __restrict__ curTU, int4* __restrict__ st_pack,
        const float* __restrict__ W_enc, unsigned char* __restrict__ wtb8,
        const float* __restrict__ W_dec, unsigned char* __restrict__ wdb8,
        const float* __restrict__ W1, unsigned short* __restrict__ w1b,
        const float* __restrict__ W2, unsigned short* __restrict__ w2b,
        int n, int nt, int SB, int TB, int DB) {
    __shared__ float tileh[64 * 128];    // 32 KB (transpose phase only)
    int bid = blockIdx.x;
    int tid = threadIdx.x;
    if (bid < SB) {
        // ---- scatter: interactions by user (int2), targets by user (int4) ----
        int i = bid * 256 + tid;
        if (i < n) {
            int u = user[i];
            int pos = atomicAdd(&curU[u], 1);
            s_pack[pos] = make_int2(item[i], __float_as_int(rating[i]));
        }
        if (i < nt) {
            int tu = t_user[i];
            int pos = atomicAdd(&curTU[tu], 1);
            st_pack[pos] = make_int4(t_item[i], __float_as_int(t_rating[i]), i, 0);
        }
    } else if (bid < SB + TB) {
        // ---- transpose W_enc [H0][NUM_ITEMS] f32 -> wtb8 [NUM_ITEMS][H0] fp8 (x64) ----
        // 128it x 64h tiles: each wave reads 2 rows x 512B contiguous.
        const int TBX = (NUM_ITEMS + 127) / 128;   // 391
        int b = bid - SB;
        int x0 = (b % TBX) * 128;       // item base
        int y0 = (b / TBX) * 64;        // h base
        int g = tid >> 5;               // 0..7 h-sub
        int m = tid & 31;               // item quad
        int it4 = x0 + m * 4;
#pragma unroll
        for (int p = 0; p < 8; ++p) {
            int hloc = p * 8 + g;
            if (it4 < NUM_ITEMS) {
                float4 v = *(const float4*)(W_enc + (size_t)(y0 + hloc) * NUM_ITEMS + it4);
                *(float4*)(tileh + hloc * 128 + m * 4) = v;
            }
        }
        __syncthreads();
        int i = tid >> 1;               // item 0..127
        int l = tid & 1;                // h-half (32 each)
        int it = x0 + i;
        if (it < NUM_ITEMS) {
            float f[32];
#pragma unroll
            for (int k = 0; k < 32; ++k)
                f[k] = tileh[(l * 32 + k) * 128 + i];
            uint4 o0, o1;
            o0.x = pkfp8_4(f[0] * FP8_SCALE, f[1] * FP8_SCALE, f[2] * FP8_SCALE, f[3] * FP8_SCALE);
            o0.y = pkfp8_4(f[4] * FP8_SCALE, f[5] * FP8_SCALE, f[6] * FP8_SCALE, f[7] * FP8_SCALE);
            o0.z = pkfp8_4(f[8] * FP8_SCALE, f[9] * FP8_SCALE, f[10] * FP8_SCALE, f[11] * FP8_SCALE);
            o0.w = pkfp8_4(f[12] * FP8_SCALE, f[13] * FP8_SCALE, f[14] * FP8_SCALE, f[15] * FP8_SCALE);
            o1.x = pkfp8_4(f[16] * FP8_SCALE, f[17] * FP8_SCALE, f[18] * FP8_SCALE, f[19] * FP8_SCALE);
            o1.y = pkfp8_4(f[20] * FP8_SCALE, f[21] * FP8_SCALE, f[22] * FP8_SCALE, f[23] * FP8_SCALE);
            o1.z = pkfp8_4(f[24] * FP8_SCALE, f[25] * FP8_SCALE, f[26] * FP8_SCALE, f[27] * FP8_SCALE);
            o1.w = pkfp8_4(f[28] * FP8_SCALE, f[29] * FP8_SCALE, f[30] * FP8_SCALE, f[31] * FP8_SCALE);
            unsigned char* dst = wtb8 + (size_t)it * H0 + y0 + l * 32;
            *(uint4*)dst = o0;
            *(uint4*)(dst + 16) = o1;
        }
    } else if (bid < SB + TB + DB) {
        // ---- W_dec f32 -> fp8 (x64), 32 elems/thread: 8 independent float4 loads in flight ----
        size_t idx = (size_t)(bid - SB - TB) * 8192 + tid * 32;
        float4 v0 = *(const float4*)(W_dec + idx);
        float4 v1 = *(const float4*)(W_dec + idx + 4);
        float4 v2 = *(const float4*)(W_dec + idx + 8);
        float4 v3 = *(const float4*)(W_dec + idx + 12);
        float4 v4 = *(const float4*)(W_dec + idx + 16);
        float4 v5 = *(const float4*)(W_dec + idx + 20);
        float4 v6 = *(const float4*)(W_dec + idx + 24);
        float4 v7 = *(const float4*)(W_dec + idx + 28);
        uint4 o0, o1;
        o0.x = pkfp8_4(v0.x * FP8_SCALE, v0.y * FP8_SCALE, v0.z * FP8_SCALE, v0.w * FP8_SCALE);
        o0.y = pkfp8_4(v1.x * FP8_SCALE, v1.y * FP8_SCALE, v1.z * FP8_SCALE, v1.w * FP8_SCALE);
        o0.z = pkfp8_4(v2.x * FP8_SCALE, v2.y * FP8_SCALE, v2.z * FP8_SCALE, v2.w * FP8_SCALE);
        o0.w = pkfp8_4(v3.x * FP8_SCALE, v3.y * FP8_SCALE, v3.z * FP8_SCALE, v3.w * FP8_SCALE);
        o1.x = pkfp8_4(v4.x * FP8_SCALE, v4.y * FP8_SCALE, v4.z * FP8_SCALE, v4.w * FP8_SCALE);
        o1.y = pkfp8_4(v5.x * FP8_SCALE, v5.y * FP8_SCALE, v5.z * FP8_SCALE, v5.w * FP8_SCALE);
        o1.z = pkfp8_4(v6.x * FP8_SCALE, v6.y * FP8_SCALE, v6.z * FP8_SCALE, v6.w * FP8_SCALE);
        o1.w = pkfp8_4(v7.x * FP8_SCALE, v7.y * FP8_SCALE, v7.z * FP8_SCALE, v7.w * FP8_SCALE);
        *(uint4*)(wdb8 + idx) = o0;
        *(uint4*)(wdb8 + idx + 16) = o1;
    } else {
        // ---- W1 / W2 cast to bf16, 64 blocks each ----
        int b2i = bid - SB - TB - DB;
        const float* src = (b2i < 64) ? W1 : W2;
        unsigned short* dst = (b2i < 64) ? w1b : w2b;
        int idx = (b2i & 63) * 2048 + tid * 8;
        float v[8];
        *(float4*)&v[0] = *(const float4*)(src + idx);
        *(float4*)&v[4] = *(const float4*)(src + idx + 4);
        *(uint4*)(dst + idx) = pack8(v);
    }
}

// ================= per-user segment sum + bias + tanh -> xb bf16 =================
// ONE WAVE PER USER (4 users/block): no barriers, no LDS, depth-2 gather pipeline.
__global__ __launch_bounds__(256) void agg_kernel(const unsigned char* __restrict__ wtb8,
                                                  const int* __restrict__ offs,
                                                  const int* __restrict__ ends,
                                                  const int2* __restrict__ s_pack,
                                                  const float* __restrict__ b_enc,
                                                  unsigned short* __restrict__ xb) {
    int wid = threadIdx.x >> 6, lane = threadIdx.x & 63;
    int u = blockIdx.x * 4 + wid;
    int j0 = offs[u], j1 = ends[u];
    float acc[8] = {};
    int j = j0;
    int2 c0 = (j < j1) ? s_pack[j] : make_int2(0, 0);
    int2 c1 = (j + 1 < j1) ? s_pack[j + 1] : make_int2(0, 0);
    while (j < j1) {
        bool has1 = (j + 1) < j1;
        uint2 v0 = ((const uint2*)(wtb8 + (size_t)c0.x * H0))[lane];
        uint2 v1 = has1 ? ((const uint2*)(wtb8 + (size_t)c1.x * H0))[lane] : make_uint2(0, 0);
        int jn = j + 2;
        int2 n0 = (jn < j1) ? s_pack[jn] : make_int2(0, 0);
        int2 n1 = (jn + 1 < j1) ? s_pack[jn + 1] : make_int2(0, 0);
        float r0 = __int_as_float(c0.y);
        float wf[8];
        fp8x4_to_f32(v0.x, wf);
        fp8x4_to_f32(v0.y, wf + 4);
#pragma unroll
        for (int e = 0; e < 8; ++e) acc[e] += wf[e] * r0;
        if (has1) {
            float r1 = __int_as_float(c1.y);
            fp8x4_to_f32(v1.x, wf);
            fp8x4_to_f32(v1.y, wf + 4);
#pragma unroll
            for (int e = 0; e < 8; ++e) acc[e] += wf[e] * r1;
        }
        c0 = n0; c1 = n1; j = jn;
    }
    float4 b0 = ((const float4*)b_enc)[lane * 2];
    float4 b1 = ((const float4*)b_enc)[lane * 2 + 1];
    float o[8];
    o[0] = tanhf(acc[0] * FP8_INV + b0.x); o[1] = tanhf(acc[1] * FP8_INV + b0.y);
    o[2] = tanhf(acc[2] * FP8_INV + b0.z); o[3] = tanhf(acc[3] * FP8_INV + b0.w);
    o[4] = tanhf(acc[4] * FP8_INV + b1.x); o[5] = tanhf(acc[5] * FP8_INV + b1.y);
    o[6] = tanhf(acc[6] * FP8_INV + b1.z); o[7] = tanhf(acc[7] * FP8_INV + b1.w);
    ((uint4*)(xb + (size_t)u * H0))[lane] = pack8(o);
}

// ================= bf16 MFMA GEMM, 128 x BN tile, tanh epilogue =================
template<int BN>
__global__ __launch_bounds__(256) void gemm_mfma(const unsigned short* __restrict__ A,
                                                 const unsigned short* __restrict__ B,
                                                 const float* __restrict__ bias,
                                                 unsigned short* __restrict__ C,
                                                 int Nn, int K) {
    constexpr int WN = BN / 32;
    constexpr int NCH = 8 + BN / 16;
    constexpr int PER = NCH / 4;
    __shared__ unsigned short Ash[128 * 32];
    __shared__ unsigned short Bsh[BN * 32];
    int tid = threadIdx.x;
    int wid = tid >> 6, lane = tid & 63;
    int wave_m = wid & 1, wave_n = wid >> 1;
    int quad = lane >> 4, l16 = lane & 15;
    int m0 = blockIdx.x * 128, n0 = blockIdx.y * BN;
    floatx4 acc[4][WN] = {};
    int srow = lane >> 2;
    int scol = (lane & 3) * 8;
    for (int k0 = 0; k0 < K; k0 += 32) {
#pragma unroll
        for (int i = 0; i < PER; ++i) {
            int c = wid * PER + i;
            if (c < 8) {
                const unsigned short* ga = A + (size_t)(m0 + c * 16 + srow) * K + k0 + scol;
                __builtin_amdgcn_global_load_lds(
                    (const __attribute__((address_space(1))) void*)ga,
                    (__attribute__((address_space(3))) void*)((__attribute__((address_space(3))) char*)Ash + c * 1024),
                    16, 0, 0);
            } else {
                const unsigned short* gb = B + (size_t)(n0 + (c - 8) * 16 + srow) * K + k0 + scol;
                __builtin_amdgcn_global_load_lds(
                    (const __attribute__((address_space(1))) void*)gb,
                    (__attribute__((address_space(3))) void*)((__attribute__((address_space(3))) char*)Bsh + (c - 8) * 1024),
                    16, 0, 0);
            }
        }
        __syncthreads();
        short8 af[4], bfr[WN];
#pragma unroll
        for (int i = 0; i < 4; ++i) {
            int ml = wave_m * 64 + i * 16 + l16;
            af[i] = ((const short8*)Ash)[ml * 4 + quad];
        }
#pragma unroll
        for (int j = 0; j < WN; ++j) {
            int nl = wave_n * (BN / 2) + j * 16 + l16;
            bfr[j] = ((const short8*)Bsh)[nl * 4 + quad];
        }
#pragma unroll
        for (int i = 0; i < 4; ++i)
#pragma unroll
            for (int j = 0; j < WN; ++j)
                acc[i][j] = __builtin_amdgcn_mfma_f32_16x16x32_bf16(af[i], bfr[j], acc[i][j], 0, 0, 0);
        __syncthreads();
    }
#pragma unroll
    for (int j = 0; j < WN; ++j) {
        int col = n0 + wave_n * (BN / 2) + j * 16 + l16;
        float bv = bias[col];
#pragma unroll
        for (int i = 0; i < 4; ++i) {
            int rowb = m0 + wave_m * 64 + i * 16 + quad * 4;
#pragma unroll
            for (int r = 0; r < 4; ++r)
                C[(size_t)(rowb + r) * Nn + col] = f2bf(tanhf(acc[i][j][r] + bv));
        }
    }
}

// ================= predict: ONE WAVE PER USER; 16-lane groups; depth-2 on targets =================
// lane = grp*16 + sl: group grp handles targets (base+grp, base+4+grp); sl covers h = sl*32..+31.
__global__ __launch_bounds__(256) void predict_kernel(const unsigned short* __restrict__ dec_b,
                                                      const unsigned char* __restrict__ wdb8,
                                                      const float* __restrict__ b_dec,
                                                      const int* __restrict__ offs,
                                                      const int* __restrict__ ends,
                                                      const int4* __restrict__ st,
                                                      float* __restrict__ pred,
                                                      float* __restrict__ partials) {
    __shared__ float wsum[4];
    int wid = threadIdx.x >> 6, lane = threadIdx.x & 63;
    int grp = lane >> 4, sl = lane & 15;
    int u = blockIdx.x * 4 + wid;
    int j0 = offs[u], j1 = ends[u];
    float sq = 0.f;
    if (j0 < j1) {
        // this user's decoded row slice: 32 bf16 (elements sl*32..+31)
        const uint4* gp = (const uint4*)(dec_b + (size_t)u * H0) + sl * 4;
        float g[32];
        unpbf8(gp[0], g);
        unpbf8(gp[1], g + 8);
        unpbf8(gp[2], g + 16);
        unpbf8(gp[3], g + 24);
        for (int base = j0; base < j1; base += 8) {
            int i0 = base + grp, i1 = base + 4 + grp;
            bool a0 = i0 < j1, a1 = i1 < j1;
            int4 t0 = st[min(i0, j1 - 1)];
            int4 t1 = st[min(i1, j1 - 1)];
            const unsigned char* w0p = wdb8 + (size_t)t0.x * H0 + sl * 32;
            const unsigned char* w1p = wdb8 + (size_t)t1.x * H0 + sl * 32;
            uint4 wa0 = *(const uint4*)w0p;
            uint4 wb0 = *(const uint4*)(w0p + 16);
            uint4 wa1 = *(const uint4*)w1p;
            uint4 wb1 = *(const uint4*)(w1p + 16);
            unsigned wu0[8] = {wa0.x, wa0.y, wa0.z, wa0.w, wb0.x, wb0.y, wb0.z, wb0.w};
            unsigned wu1[8] = {wa1.x, wa1.y, wa1.z, wa1.w, wb1.x, wb1.y, wb1.z, wb1.w};
            float s0 = 0.f, s1 = 0.f;
#pragma unroll
            for (int q = 0; q < 8; ++q) {
                float wf[4];
                fp8x4_to_f32(wu0[q], wf);
                s0 += g[q * 4 + 0] * wf[0] + g[q * 4 + 1] * wf[1]
                    + g[q * 4 + 2] * wf[2] + g[q * 4 + 3] * wf[3];
                fp8x4_to_f32(wu1[q], wf);
                s1 += g[q * 4 + 0] * wf[0] + g[q * 4 + 1] * wf[1]
                    + g[q * 4 + 2] * wf[2] + g[q * 4 + 3] * wf[3];
            }
#pragma unroll
            for (int off = 1; off < 16; off <<= 1) {
                s0 += __shfl_xor(s0, off, 64);
                s1 += __shfl_xor(s1, off, 64);
            }
            if (sl == 0) {
                if (a0) {
                    float p = s0 * FP8_INV + b_dec[t0.x];
                    pred[t0.z] = p;
                    float d = p - __int_as_float(t0.y);
                    sq += d * d;
                }
                if (a1) {
                    float p = s1 * FP8_INV + b_dec[t1.x];
                    pred[t1.z] = p;
                    float d = p - __int_as_float(t1.y);
                    sq += d * d;
                }
            }
        }
    }
    // combine the 4 group-leader lanes (sl==0) of this wave
    sq += __shfl_xor(sq, 16, 64);
    sq += __shfl_xor(sq, 32, 64);
    if (lane == 0) wsum[wid] = sq;
    __syncthreads();
    if (threadIdx.x == 0)
        partials[blockIdx.x] = wsum[0] + wsum[1] + wsum[2] + wsum[3];
}

__global__ void loss_reduce(const float* __restrict__ partials, float* __restrict__ out_loss,
                            int nPart, float invNT) {
    __shared__ float s[256];
    int t = threadIdx.x;
    float a = 0.f;
    const float4* p4 = (const float4*)partials;
    int n4 = nPart >> 2;
    for (int i = t; i < n4; i += 256) {
        float4 v = p4[i];
        a += v.x + v.y + v.z + v.w;
    }
    for (int i = (n4 << 2) + t; i < nPart; i += 256) a += partials[i];
    s[t] = a;
    __syncthreads();
    for (int off = 128; off; off >>= 1) {
        if (t < off) s[t] += s[t + off];
        __syncthreads();
    }
    if (t == 0) out_loss[0] = s[0] * invNT;
}

extern "C" void kernel_launch(void* const* d_in, const int* in_sizes, int n_in,
                              void* d_out, int out_size, void* d_ws, size_t ws_size,
                              hipStream_t stream) {
    const int* user = (const int*)d_in[0];
    const int* item = (const int*)d_in[1];
    const float* rating = (const float*)d_in[2];
    const int* t_user = (const int*)d_in[3];
    const int* t_item = (const int*)d_in[4];
    const float* t_rating = (const float*)d_in[5];
    const float* W_enc = (const float*)d_in[6];
    const float* b_enc = (const float*)d_in[7];
    const float* W1 = (const float*)d_in[8];
    const float* b1 = (const float*)d_in[9];
    const float* W2 = (const float*)d_in[10];
    const float* b2 = (const float*)d_in[11];
    const float* W_dec = (const float*)d_in[12];
    const float* b_dec = (const float*)d_in[13];
    const int N = in_sizes[0];
    const int NT = in_sizes[3];

    char* ws = (char*)d_ws;
    size_t off = 0;
    auto alloc = [&](size_t bytes) {
        void* p = ws + off;
        off = (off + bytes + 255) & ~(size_t)255;
        return p;
    };
    unsigned char* wtb8 = (unsigned char*)alloc((size_t)NUM_ITEMS * H0);        // 25.6 MB
    unsigned char* wdb8 = (unsigned char*)alloc((size_t)NUM_ITEMS * H0);        // 25.6 MB
    unsigned short* xb = (unsigned short*)alloc((size_t)NUM_USERS * H0 * 2);    // 16 MB
    unsigned short* enc_b = (unsigned short*)alloc((size_t)NUM_USERS * LAT * 2);// 8 MB
    unsigned short* dec_b = (unsigned short*)alloc((size_t)NUM_USERS * H0 * 2); // 16 MB
    unsigned short* w1b = (unsigned short*)alloc((size_t)LAT * H0 * 2);
    unsigned short* w2b = (unsigned short*)alloc((size_t)H0 * LAT * 2);
    int* cntU = (int*)alloc((size_t)NUM_USERS * 2 * 4);
    int* cntTU = cntU + NUM_USERS;
    int* offsU = (int*)alloc((size_t)NUM_USERS * 4);
    int* curU = (int*)alloc((size_t)NUM_USERS * 4);
    int* offsTU = (int*)alloc((size_t)NUM_USERS * 4);
    int* curTU = (int*)alloc((size_t)NUM_USERS * 4);
    int2* s_pack = (int2*)alloc((size_t)N * 8);
    int4* st_pack = (int4*)alloc((size_t)NT * 16);
    float* partials = (float*)alloc((size_t)(NUM_USERS / 4) * 4);

    float* pred = (float*)d_out;
    float* loss = pred + NT;

    const int maxNNT = N > NT ? N : NT;
    const int SB = (maxNNT + 255) / 256;                 // 1024 scatter blocks
    const int TBX = (NUM_ITEMS + 127) / 128;             // 391
    const int TB = TBX * (H0 / 64);                      // 3128 transpose blocks
    const int DB = (NUM_ITEMS * H0) / 8192;              // 3125 W_dec cast blocks
    const int WB = 128;                                  // W1+W2 cast blocks

    hipMemsetAsync(cntU, 0, (size_t)NUM_USERS * 2 * 4, stream);
    count_kernel<<<(maxNNT + 1023) / 1024, 256, 0, stream>>>(user, cntU, t_user, cntTU, N, NT);
    scan_kernel<<<2, 1024, 0, stream>>>(cntU, offsU, curU, cntTU, offsTU, curTU);
    mega_kernel<<<SB + TB + DB + WB, 256, 0, stream>>>(
        user, item, rating, curU, s_pack,
        t_user, t_item, t_rating, curTU, st_pack,
        W_enc, wtb8, W_dec, wdb8, W1, w1b, W2, w2b,
        N, NT, SB, TB, DB);
    agg_kernel<<<NUM_USERS / 4, 256, 0, stream>>>(wtb8, offsU, curU, s_pack, b_enc, xb);
    gemm_mfma<64><<<dim3(NUM_USERS / 128, LAT / 64), 256, 0, stream>>>(xb, w1b, b1, enc_b, LAT, H0);
    gemm_mfma<64><<<dim3(NUM_USERS / 128, H0 / 64), 256, 0, stream>>>(enc_b, w2b, b2, dec_b, H0, LAT);
    predict_kernel<<<NUM_USERS / 4, 256, 0, stream>>>(dec_b, wdb8, b_dec, offsTU, curTU, st_pack, pred, partials);
    loss_reduce<<<1, 256, 0, stream>>>(partials, loss, NUM_USERS / 4, 1.0f / NT);
}